// Round 7
// baseline (211.470 us; speedup 1.0000x reference)
//
#include <hip/hip_runtime.h>
#include <hip/hip_bf16.h>
#include <stdint.h>

typedef __bf16 bf16_t;
typedef __bf16 bf16x8 __attribute__((ext_vector_type(8)));
typedef __bf16 bf16x4 __attribute__((ext_vector_type(4)));
typedef float f32x4 __attribute__((ext_vector_type(4)));

#define GLD_LDS16(src, dst)                                                              \
  __builtin_amdgcn_global_load_lds((const __attribute__((address_space(1))) void*)(src), \
                                   (__attribute__((address_space(3))) void*)(dst), 16, 0, 0)

// ---------------------------------------------------------------------------
// fp32 -> bf16 convert (weights only). blockIdx.y = segment.
// ---------------------------------------------------------------------------
struct CvtArgs {
  const float* src[4];
  bf16_t* dst[4];
  long n4[4];
};

__global__ __launch_bounds__(256) void cvt_all(CvtArgs a) {
  const int seg = blockIdx.y;
  const float* __restrict__ in = a.src[seg];
  bf16_t* __restrict__ out = a.dst[seg];
  const long n4 = a.n4[seg];
  long i = (long)blockIdx.x * blockDim.x + threadIdx.x;
  const long stride = (long)gridDim.x * blockDim.x;
  for (; i < n4; i += stride) {
    float4 v = ((const float4*)in)[i];
    bf16x4 o;
    o[0] = (bf16_t)v.x; o[1] = (bf16_t)v.y; o[2] = (bf16_t)v.z; o[3] = (bf16_t)v.w;
    ((bf16x4*)out)[i] = o;
  }
}

// ---------------------------------------------------------------------------
// Causal row softmax, in-place, bounded: row i only touches
// j < jmax = (floor(i/128)+1)*128 (PV's KBOUND never reads past jmax).
// ---------------------------------------------------------------------------
__global__ __launch_bounds__(256) void softmax_causal(bf16_t* __restrict__ S, int n, long sB) {
  const int i = blockIdx.x;
  const int z = blockIdx.y;
  bf16_t* row = S + (long)z * sB + (long)i * n;
  const int t = threadIdx.x;
  const int j0 = t << 3;
  const int jmax = ((i >> 7) + 1) << 7;
  const bool active = j0 < jmax;

  float vals[8];
  float mx = -3.0e38f;
  if (active) {
    bf16x8 vv = ((const bf16x8*)row)[t];
#pragma unroll
    for (int e = 0; e < 8; ++e) {
      float v = (j0 + e <= i) ? (float)vv[e] : -3.0e38f;
      vals[e] = v;
      mx = fmaxf(mx, v);
    }
  }
#pragma unroll
  for (int off = 32; off; off >>= 1) mx = fmaxf(mx, __shfl_xor(mx, off));
  __shared__ float redm[4];
  if ((t & 63) == 0) redm[t >> 6] = mx;
  __syncthreads();
  mx = fmaxf(fmaxf(redm[0], redm[1]), fmaxf(redm[2], redm[3]));

  float sum = 0.f;
  if (active) {
#pragma unroll
    for (int e = 0; e < 8; ++e) {
      float p = (j0 + e <= i) ? __expf(vals[e] - mx) : 0.f;
      vals[e] = p;
      sum += p;
    }
  }
#pragma unroll
  for (int off = 32; off; off >>= 1) sum += __shfl_xor(sum, off);
  __shared__ float reds[4];
  if ((t & 63) == 0) reds[t >> 6] = sum;
  __syncthreads();
  sum = reds[0] + reds[1] + reds[2] + reds[3];
  const float inv = 1.0f / sum;

  if (active) {
    bf16x8 o;
#pragma unroll
    for (int e = 0; e < 8; ++e) o[e] = (bf16_t)(vals[e] * inv);
    ((bf16x8*)row)[t] = o;
  }
}

// ---------------------------------------------------------------------------
// XCD-chunked bijective remap (requires nwg % 8 == 0; all grids comply).
// ---------------------------------------------------------------------------
__device__ __forceinline__ void xcd_remap(int& bx, int& by, int& bz) {
  const int gx = gridDim.x, gy = gridDim.y;
  int lin = (blockIdx.z * gy + blockIdx.y) * gx + blockIdx.x;
  const int nwg = gx * gy * (int)gridDim.z;
  lin = (lin & 7) * (nwg >> 3) + (lin >> 3);
  bx = lin % gx;
  const int rem = lin / gx;
  by = rem % gy;
  bz = rem / gy;
}

// ---------------------------------------------------------------------------
// 128x128 m97-structure GEMM: C = alpha*A[M,K]*B[N,K]^T (+bias). bf16 inputs.
// CAUSAL_SKIP: skip tiles above the diagonal (scores). KBOUND: K-loop bounded
// by n0+128 (PV; P[i][j]=0 for j>i so tiles beyond contribute nothing).
// ---------------------------------------------------------------------------
template <bool BF16_OUT, bool BIAS, bool CAUSAL_SKIP, bool KBOUND>
__global__ __launch_bounds__(256, 4) void gemm_bt(const bf16_t* __restrict__ Ag,
                                                  const bf16_t* __restrict__ Bg,
                                                  const float* __restrict__ bias,
                                                  void* __restrict__ Cout,
                                                  int N, int K, float alpha,
                                                  long sAb, long sBb, long sCb, int eltC) {
  int bx, by, bz;
  xcd_remap(bx, by, bz);
  const int m0 = by << 7, n0 = bx << 7;
  if (CAUSAL_SKIP && n0 > m0 + 127) return;

  const bf16_t* A = Ag + (long)bz * sAb;
  const bf16_t* B = Bg + (long)bz * sBb;
  void* Cv = (char*)Cout + (long)bz * sCb * eltC;

  int KT = K >> 5;
  if (KBOUND) {
    int kb = (n0 + 128) >> 5;
    if (kb < KT) KT = kb;
  }

  __shared__ __align__(16) bf16_t As[128 * 32];
  __shared__ __align__(16) bf16_t Bs[128 * 32];

  const int t = threadIdx.x;
  const int l = t & 63;
  const int w = t >> 6;
  const int wr = w >> 1, wc = w & 1;

  const int c0 = t, c1 = t + 256;
  const bf16_t* a_src0 = A + (long)(m0 + (c0 >> 2)) * K + ((c0 & 3) << 3);
  const bf16_t* a_src1 = A + (long)(m0 + (c1 >> 2)) * K + ((c1 & 3) << 3);
  const bf16_t* b_src0 = B + (long)(n0 + (c0 >> 2)) * K + ((c0 & 3) << 3);
  const bf16_t* b_src1 = B + (long)(n0 + (c1 >> 2)) * K + ((c1 & 3) << 3);
  char* const asb = (char*)As;
  char* const bsb = (char*)Bs;
  char* const a_dst0 = asb + w * 1024;
  char* const a_dst1 = asb + 4096 + w * 1024;
  char* const b_dst0 = bsb + w * 1024;
  char* const b_dst1 = bsb + 4096 + w * 1024;

  const int r16 = l & 15, kg = l >> 4;
  int aoff[4], boff[4];
#pragma unroll
  for (int mi = 0; mi < 4; ++mi) aoff[mi] = (((wr * 64 + mi * 16 + r16) * 32) + kg * 8) * 2;
#pragma unroll
  for (int ni = 0; ni < 4; ++ni) boff[ni] = (((wc * 64 + ni * 16 + r16) * 32) + kg * 8) * 2;

  f32x4 acc[4][4] = {};

  for (int kt = 0; kt < KT; ++kt) {
    __syncthreads();
    GLD_LDS16(a_src0, a_dst0);
    GLD_LDS16(a_src1, a_dst1);
    GLD_LDS16(b_src0, b_dst0);
    GLD_LDS16(b_src1, b_dst1);
    a_src0 += 32; a_src1 += 32; b_src0 += 32; b_src1 += 32;
    __syncthreads();

    bf16x8 af[4], bfr[4];
#pragma unroll
    for (int mi = 0; mi < 4; ++mi) af[mi] = *(const bf16x8*)(asb + aoff[mi]);
#pragma unroll
    for (int ni = 0; ni < 4; ++ni) bfr[ni] = *(const bf16x8*)(bsb + boff[ni]);
#pragma unroll
    for (int mi = 0; mi < 4; ++mi)
#pragma unroll
      for (int ni = 0; ni < 4; ++ni)
        acc[mi][ni] = __builtin_amdgcn_mfma_f32_16x16x32_bf16(af[mi], bfr[ni], acc[mi][ni], 0, 0, 0);
  }

  const int rowbase = m0 + wr * 64 + ((l >> 4) << 2);
  const int colbase = n0 + wc * 64 + (l & 15);
  if constexpr (BF16_OUT) {
    bf16_t* C = (bf16_t*)Cv;
#pragma unroll
    for (int mi = 0; mi < 4; ++mi)
#pragma unroll
      for (int ni = 0; ni < 4; ++ni) {
        const int col = colbase + ni * 16;
        float badd = 0.f;
        if constexpr (BIAS) badd = bias[col];
#pragma unroll
        for (int j = 0; j < 4; ++j) {
          float v = acc[mi][ni][j] * alpha + badd;
          C[(long)(rowbase + mi * 16 + j) * N + col] = (bf16_t)v;
        }
      }
  } else {
    float* C = (float*)Cv;
#pragma unroll
    for (int mi = 0; mi < 4; ++mi)
#pragma unroll
      for (int ni = 0; ni < 4; ++ni) {
        const int col = colbase + ni * 16;
        float badd = 0.f;
        if constexpr (BIAS) badd = bias[col];
#pragma unroll
        for (int j = 0; j < 4; ++j) {
          float v = acc[mi][ni][j] * alpha + badd;
          C[(long)(rowbase + mi * 16 + j) * N + col] = v;
        }
      }
  }
}

// ---------------------------------------------------------------------------
// QKV projection, m97 structure, A staged DIRECTLY as fp32 via global_load_lds
// into a 16 KB XOR-swizzled LDS tile ([128][32] f32, phys = logical ^
// ((row&7)<<4) on the byte offset); converted fp32->bf16 at LDS->reg read.
// Round-trip verified: row 3 col 9 -> chunk 25 byte 404 both directions.
// Read pattern: 64 lanes hit 64 distinct 16B slots -> conflict-free.
// B = bf16 weights via linear DMA (proven path). z selects op; z==2 (V)
// writes its output transposed into vpT[b][d][n].
// ---------------------------------------------------------------------------
struct QkvArgsF {
  const float* A[3];
  const bf16_t* W[3];
  const float* bias[3];
  bf16_t* C[3];
};

__global__ __launch_bounds__(256, 4) void gemm_qkv_f32dma(QkvArgsF ga, int N, int K) {
  int bx, by, bz;
  xcd_remap(bx, by, bz);
  const int m0 = by << 7, n0 = bx << 7;

  const float* __restrict__ A = ga.A[bz];
  const bf16_t* __restrict__ B = ga.W[bz];
  const float* __restrict__ bias = ga.bias[bz];
  const int KT = K >> 5;

  __shared__ __align__(16) char lds[24576];  // A f32 16KB + B bf16 8KB
  char* const asb = lds;
  char* const bsb = lds + 16384;

  const int t = threadIdx.x;
  const int l = t & 63;
  const int w = t >> 6;
  const int wr = w >> 1, wc = w & 1;

  // A DMA sources: issue i stages chunk c = i*256 + t to linear dest c*16;
  // source column pre-swizzled so the swizzled READ sees logical layout.
  const float* a_src[4];
#pragma unroll
  for (int i = 0; i < 4; ++i) {
    const int c = i * 256 + t;
    const int row = c >> 3;                   // 8 x 16B chunks per 128B row
    const int lo16 = (c & 7) ^ (row & 7);     // inverse swizzle (involution)
    a_src[i] = A + (long)(m0 + row) * K + lo16 * 4;
  }
  // B DMA (bf16, linear): chunk c -> row c/4, k (c%4)*8
  const int c0 = t, c1 = t + 256;
  const bf16_t* b_src0 = B + (long)(n0 + (c0 >> 2)) * K + ((c0 & 3) << 3);
  const bf16_t* b_src1 = B + (long)(n0 + (c1 >> 2)) * K + ((c1 & 3) << 3);
  char* const b_dst0 = bsb + w * 1024;
  char* const b_dst1 = bsb + 4096 + w * 1024;

  const int r16 = l & 15, kg = l >> 4;
  int aoff[4], boff[4];
#pragma unroll
  for (int mi = 0; mi < 4; ++mi) {
    const int row = wr * 64 + mi * 16 + r16;
    aoff[mi] = (row * 128 + kg * 32) ^ ((row & 7) << 4);
  }
#pragma unroll
  for (int ni = 0; ni < 4; ++ni) boff[ni] = (((wc * 64 + ni * 16 + r16) * 32) + kg * 8) * 2;

  f32x4 acc[4][4] = {};

  for (int kt = 0; kt < KT; ++kt) {
    __syncthreads();
#pragma unroll
    for (int i = 0; i < 4; ++i) {
      GLD_LDS16(a_src[i], asb + i * 4096 + w * 1024);
      a_src[i] += 32;
    }
    GLD_LDS16(b_src0, b_dst0);
    GLD_LDS16(b_src1, b_dst1);
    b_src0 += 32; b_src1 += 32;
    __syncthreads();

    bf16x8 af[4], bfr[4];
#pragma unroll
    for (int mi = 0; mi < 4; ++mi) {
      f32x4 lo4 = *(const f32x4*)(asb + aoff[mi]);
      f32x4 hi4 = *(const f32x4*)(asb + (aoff[mi] ^ 16));
      af[mi][0] = (bf16_t)lo4[0]; af[mi][1] = (bf16_t)lo4[1];
      af[mi][2] = (bf16_t)lo4[2]; af[mi][3] = (bf16_t)lo4[3];
      af[mi][4] = (bf16_t)hi4[0]; af[mi][5] = (bf16_t)hi4[1];
      af[mi][6] = (bf16_t)hi4[2]; af[mi][7] = (bf16_t)hi4[3];
    }
#pragma unroll
    for (int ni = 0; ni < 4; ++ni) bfr[ni] = *(const bf16x8*)(bsb + boff[ni]);
#pragma unroll
    for (int mi = 0; mi < 4; ++mi)
#pragma unroll
      for (int ni = 0; ni < 4; ++ni)
        acc[mi][ni] = __builtin_amdgcn_mfma_f32_16x16x32_bf16(af[mi], bfr[ni], acc[mi][ni], 0, 0, 0);
  }

  const int rowbase = m0 + wr * 64 + ((l >> 4) << 2);
  const int colbase = n0 + wc * 64 + (l & 15);
  if (bz < 2) {
    bf16_t* C = ga.C[bz];  // [8192,1024]
#pragma unroll
    for (int mi = 0; mi < 4; ++mi)
#pragma unroll
      for (int ni = 0; ni < 4; ++ni) {
        const int col = colbase + ni * 16;
        const float badd = bias[col];
#pragma unroll
        for (int j = 0; j < 4; ++j)
          C[(long)(rowbase + mi * 16 + j) * N + col] = (bf16_t)(acc[mi][ni][j] + badd);
      }
  } else {
    bf16_t* C = ga.C[2];  // vpT: per-batch [1024][2048]
#pragma unroll
    for (int mi = 0; mi < 4; ++mi)
#pragma unroll
      for (int ni = 0; ni < 4; ++ni) {
        const int col = colbase + ni * 16;
        const float badd = bias[col];
        const int row0 = rowbase + mi * 16;
        const int batch = row0 >> 11, nr = row0 & 2047;
        bf16x4 o;
#pragma unroll
        for (int j = 0; j < 4; ++j) o[j] = (bf16_t)(acc[mi][ni][j] + badd);
        *(bf16x4*)(C + (long)batch * (2048 * 1024) + (long)col * 2048 + nr) = o;
      }
  }
}

// ---------------------------------------------------------------------------
extern "C" void kernel_launch(void* const* d_in, const int* in_sizes, int n_in,
                              void* d_out, int out_size, void* d_ws, size_t ws_size,
                              hipStream_t stream) {
  const int b = 4, n = 2048, d = 1024;
  const long nd  = (long)n * d;
  const long bn  = (long)b * n;
  const long bnd = bn * d;
  const long ddl = (long)d * d;
  const long nn  = (long)n * n;

  const float* q  = (const float*)d_in[0];
  const float* k  = (const float*)d_in[1];
  const float* v  = (const float*)d_in[2];
  const float* Wq = (const float*)d_in[3];
  const float* bq = (const float*)d_in[4];
  const float* Wk = (const float*)d_in[5];
  const float* bk = (const float*)d_in[6];
  const float* Wv = (const float*)d_in[7];
  const float* bv = (const float*)d_in[8];
  const float* Wo = (const float*)d_in[9];
  const float* bo = (const float*)d_in[10];

  bf16_t* ws  = (bf16_t*)d_ws;
  bf16_t* WqB = ws;
  bf16_t* WkB = WqB + ddl;
  bf16_t* WvB = WkB + ddl;
  bf16_t* WoB = WvB + ddl;
  bf16_t* qpB = WoB + ddl;
  bf16_t* kpB = qpB + bnd;
  bf16_t* vpT = kpB + bnd;       // per-batch [d][n] (written by V-proj epilogue)
  bf16_t* S   = vpT + bnd;
  bf16_t* yT  = S + (long)b * nn;
  const size_t need = (size_t)(4 * ddl + 4 * bnd + (long)b * nn) * 2;
  if (ws_size < need) return;

  dim3 blk(256);

  // fp32 -> bf16 converts: weights only
  CvtArgs ca;
  ca.src[0] = Wq; ca.dst[0] = WqB; ca.n4[0] = ddl / 4;
  ca.src[1] = Wk; ca.dst[1] = WkB; ca.n4[1] = ddl / 4;
  ca.src[2] = Wv; ca.dst[2] = WvB; ca.n4[2] = ddl / 4;
  ca.src[3] = Wo; ca.dst[3] = WoB; ca.n4[3] = ddl / 4;
  cvt_all<<<dim3(256, 4), blk, 0, stream>>>(ca);

  // fused QKV projections from fp32 inputs (A via swizzled fp32 DMA)
  QkvArgsF qa;
  qa.A[0] = q; qa.W[0] = WqB; qa.bias[0] = bq; qa.C[0] = qpB;
  qa.A[1] = k; qa.W[1] = WkB; qa.bias[1] = bk; qa.C[1] = kpB;
  qa.A[2] = v; qa.W[2] = WvB; qa.bias[2] = bv; qa.C[2] = vpT;
  gemm_qkv_f32dma<<<dim3(d / 128, bn / 128, 3), blk, 0, stream>>>(qa, d, d);

  // scores: S[z] = qp[z] x kp[z]^T * (1/32), 128^2 kernel, causal tile-skip
  gemm_bt<true, false, true, false><<<dim3(n / 128, n / 128, b), blk, 0, stream>>>(
      qpB, kpB, nullptr, S, n, d, 0.03125f, nd, nd, nn, 2);

  // causal softmax in place (bounded to the straddle tile)
  softmax_causal<<<dim3(n, b), blk, 0, stream>>>(S, n, nn);

  // yT[z] = vpT[z] x P[z]^T   (K bounded per N-tile by causality)
  gemm_bt<true, false, false, true><<<dim3(n / 128, d / 128, b), blk, 0, stream>>>(
      vpT, S, nullptr, yT, n, n, 1.f, nd, nn, nd, 2);

  // out = y2 x Wo^T + bo ; y2 flat == yT flat, fp32 out
  gemm_bt<false, true, false, false><<<dim3(d / 128, bn / 128, 1), blk, 0, stream>>>(
      yT, WoB, bo, (float*)d_out, d, d, 1.f, 0, 0, 0, 4);
}